// Round 2
// baseline (707.738 us; speedup 1.0000x reference)
//
#include <hip/hip_runtime.h>

// DiagLRConv: out[n,o,h,w] = sum_{k=0..4} sum_{i=0..15} fw[o,i,k] * x[n,i,h+k-2,w+k-2]
// x: (16,16,512,512) fp32, fw: (16,16,5) fp32, out: (16,16,512,512) fp32.

#define HH    512
#define WW    512
#define CH    16
#define KK    5
#define IMG   (HH * WW)     // 262144
#define CHIMG (CH * IMG)

typedef float f4 __attribute__((ext_vector_type(4)));
typedef f4 __attribute__((aligned(4))) f4u;   // 4B-aligned vector load (shifted)

// ---------------- main kernel: interior (clamped borders, fixed up later) ---
__global__ __launch_bounds__(256, 4)
void diag_conv_main(const float* __restrict__ x,
                    const float* __restrict__ fw,
                    float* __restrict__ out)
{
    __shared__ __align__(16) float Wlds[KK][CH][CH];   // [k][o][i]
    const int tid = threadIdx.x;
    for (int idx = tid; idx < KK * CH * CH; idx += 256) {
        int k   = idx >> 8;        // / 256
        int rem = idx & 255;
        int o   = rem >> 4;
        int i   = rem & 15;
        Wlds[k][o][i] = fw[(o * CH + i) * KK + k];
    }
    __syncthreads();

    // Bijective XCD swizzle over 4096 blocks (8 XCDs x 512 contiguous ids).
    // Each XCD gets 2 full images; neighbor-ht blocks co-resident -> L2 halo hits.
    const int bid = blockIdx.x;
    const int swz = ((bid & 7) << 9) | (bid >> 3);
    const int wt  = swz & 1;          // w tile (0..1)
    const int ht  = (swz >> 1) & 127; // h tile (0..127)
    const int n   = swz >> 8;         // image (0..15)

    const int wave = __builtin_amdgcn_readfirstlane(tid >> 6);  // SGPR
    const int lane = tid & 63;
    const int h    = ht * 4 + wave;          // wave-uniform
    const int w0   = wt * 256 + lane * 4;    // 4 contiguous px per lane

    const float* __restrict__ xn = x + (size_t)n * CHIMG;

    f4 acc[CH];
#pragma unroll
    for (int o = 0; o < CH; ++o) acc[o] = (f4){0.f, 0.f, 0.f, 0.f};

#pragma unroll 1
    for (int k = 0; k < KK; ++k) {
        const int hh = h + k - 2;                       // wave-uniform
        if ((unsigned)hh >= (unsigned)HH) continue;     // uniform branch

        int ww0 = w0 + k - 2;
        ww0 = ww0 < 0 ? 0 : (ww0 > WW - 4 ? WW - 4 : ww0);  // clamp; borders fixed up
        const float* __restrict__ rowu = xn + (size_t)hh * WW;  // uniform base

#pragma unroll
        for (int c = 0; c < 4; ++c) {   // channels in chunks of 4
            f4 xv0 = *(const f4u*)(rowu + (size_t)(4 * c + 0) * IMG + ww0);
            f4 xv1 = *(const f4u*)(rowu + (size_t)(4 * c + 1) * IMG + ww0);
            f4 xv2 = *(const f4u*)(rowu + (size_t)(4 * c + 2) * IMG + ww0);
            f4 xv3 = *(const f4u*)(rowu + (size_t)(4 * c + 3) * IMG + ww0);
#pragma unroll
            for (int o = 0; o < CH; ++o) {
                f4 wq = *(const f4*)&Wlds[k][o][4 * c];   // broadcast ds_read_b128
                acc[o].x = fmaf(wq.x, xv0.x, acc[o].x);
                acc[o].y = fmaf(wq.x, xv0.y, acc[o].y);
                acc[o].z = fmaf(wq.x, xv0.z, acc[o].z);
                acc[o].w = fmaf(wq.x, xv0.w, acc[o].w);
                acc[o].x = fmaf(wq.y, xv1.x, acc[o].x);
                acc[o].y = fmaf(wq.y, xv1.y, acc[o].y);
                acc[o].z = fmaf(wq.y, xv1.z, acc[o].z);
                acc[o].w = fmaf(wq.y, xv1.w, acc[o].w);
                acc[o].x = fmaf(wq.z, xv2.x, acc[o].x);
                acc[o].y = fmaf(wq.z, xv2.y, acc[o].y);
                acc[o].z = fmaf(wq.z, xv2.z, acc[o].z);
                acc[o].w = fmaf(wq.z, xv2.w, acc[o].w);
                acc[o].x = fmaf(wq.w, xv3.x, acc[o].x);
                acc[o].y = fmaf(wq.w, xv3.y, acc[o].y);
                acc[o].z = fmaf(wq.w, xv3.z, acc[o].z);
                acc[o].w = fmaf(wq.w, xv3.w, acc[o].w);
            }
        }
    }

    float* __restrict__ on = out + (size_t)n * CHIMG + (size_t)h * WW + w0;
#pragma unroll
    for (int o = 0; o < CH; ++o)
        *(f4*)(on + (size_t)o * IMG) = acc[o];   // 16B aligned
}

// ---------------- fixup kernel: recompute w in {0..3, 508..511} exactly -----
__global__ void diag_conv_fixup(const float* __restrict__ x,
                                const float* __restrict__ fw,
                                float* __restrict__ out)
{
    const int h  = blockIdx.x;
    const int n  = blockIdx.y;
    const int o  = threadIdx.x >> 3;
    const int wi = threadIdx.x & 7;
    const int w  = wi < 4 ? wi : (WW - 8 + wi);   // 0..3 or 508..511

    float s = 0.f;
#pragma unroll
    for (int k = 0; k < KK; ++k) {
        const int hh = h + k - 2;
        const int ww = w + k - 2;
        if ((unsigned)hh >= (unsigned)HH || (unsigned)ww >= (unsigned)WW) continue;
        const float* __restrict__ xp = x + (size_t)n * CHIMG + (size_t)hh * WW + ww;
#pragma unroll
        for (int i = 0; i < CH; ++i)
            s = fmaf(fw[(o * CH + i) * KK + k], xp[(size_t)i * IMG], s);
    }
    out[(size_t)(n * CH + o) * IMG + (size_t)h * WW + w] = s;
}

extern "C" void kernel_launch(void* const* d_in, const int* in_sizes, int n_in,
                              void* d_out, int out_size, void* d_ws, size_t ws_size,
                              hipStream_t stream)
{
    const float* x  = (const float*)d_in[0];
    const float* fw = (const float*)d_in[1];
    float* out      = (float*)d_out;

    diag_conv_main<<<dim3(4096), dim3(256), 0, stream>>>(x, fw, out);
    diag_conv_fixup<<<dim3(HH, 16), dim3(128), 0, stream>>>(x, fw, out);
}

// Round 3
// 234.743 us; speedup vs baseline: 3.0150x; 3.0150x over previous
//
#include <hip/hip_runtime.h>

// DiagLRConv: out[n,o,h,w] = sum_{k=0..4} sum_{i=0..15} fw[o,i,k] * x[n,i,h+k-2,w+k-2]
// x: (16,16,512,512) fp32, fw: (16,16,5) fp32, out: (16,16,512,512) fp32.

#define HH    512
#define WW    512
#define CH    16
#define KK    5
#define IMG   (HH * WW)     // 262144
#define CHIMG (CH * IMG)

typedef float f4 __attribute__((ext_vector_type(4)));
typedef f4 __attribute__((aligned(4))) f4u;   // 4B-aligned vector load (shifted)

// ---------------- main kernel: interior (clamped borders, fixed up later) ---
// NOTE: __launch_bounds__(256, 4) made the allocator cap VGPRs at 64 -> acc[]
// spilled to scratch -> 2.7 GB of HBM traffic, 3x slowdown (round 2).
// Live set is ~100 VGPRs (64 acc + 16 xv + wq + addr); leave the cap off.
__global__ __launch_bounds__(256)
void diag_conv_main(const float* __restrict__ x,
                    const float* __restrict__ fw,
                    float* __restrict__ out)
{
    __shared__ __align__(16) float Wlds[KK][CH][CH];   // [k][o][i]
    const int tid = threadIdx.x;
    for (int idx = tid; idx < KK * CH * CH; idx += 256) {
        int k   = idx >> 8;        // / 256
        int rem = idx & 255;
        int o   = rem >> 4;
        int i   = rem & 15;
        Wlds[k][o][i] = fw[(o * CH + i) * KK + k];
    }
    __syncthreads();

    // Bijective XCD swizzle over 4096 blocks (8 XCDs x 512 contiguous ids).
    // Each XCD gets 2 full images; neighbor-ht blocks co-resident -> L2 halo hits.
    const int bid = blockIdx.x;
    const int swz = ((bid & 7) << 9) | (bid >> 3);
    const int wt  = swz & 1;          // w tile (0..1)
    const int ht  = (swz >> 1) & 127; // h tile (0..127)
    const int n   = swz >> 8;         // image (0..15)

    const int wave = __builtin_amdgcn_readfirstlane(tid >> 6);  // SGPR
    const int lane = tid & 63;
    const int h    = ht * 4 + wave;          // wave-uniform
    const int w0   = wt * 256 + lane * 4;    // 4 contiguous px per lane

    const float* __restrict__ xn = x + (size_t)n * CHIMG;

    f4 acc[CH];
#pragma unroll
    for (int o = 0; o < CH; ++o) acc[o] = (f4){0.f, 0.f, 0.f, 0.f};

#pragma unroll 1
    for (int k = 0; k < KK; ++k) {
        const int hh = h + k - 2;                       // wave-uniform
        if ((unsigned)hh >= (unsigned)HH) continue;     // uniform branch

        int ww0 = w0 + k - 2;
        ww0 = ww0 < 0 ? 0 : (ww0 > WW - 4 ? WW - 4 : ww0);  // clamp; borders fixed up
        const float* __restrict__ rowu = xn + (size_t)hh * WW;  // uniform base

#pragma unroll
        for (int c = 0; c < 4; ++c) {   // channels in chunks of 4
            f4 xv0 = *(const f4u*)(rowu + (size_t)(4 * c + 0) * IMG + ww0);
            f4 xv1 = *(const f4u*)(rowu + (size_t)(4 * c + 1) * IMG + ww0);
            f4 xv2 = *(const f4u*)(rowu + (size_t)(4 * c + 2) * IMG + ww0);
            f4 xv3 = *(const f4u*)(rowu + (size_t)(4 * c + 3) * IMG + ww0);
#pragma unroll
            for (int o = 0; o < CH; ++o) {
                f4 wq = *(const f4*)&Wlds[k][o][4 * c];   // broadcast ds_read_b128
                acc[o].x = fmaf(wq.x, xv0.x, acc[o].x);
                acc[o].y = fmaf(wq.x, xv0.y, acc[o].y);
                acc[o].z = fmaf(wq.x, xv0.z, acc[o].z);
                acc[o].w = fmaf(wq.x, xv0.w, acc[o].w);
                acc[o].x = fmaf(wq.y, xv1.x, acc[o].x);
                acc[o].y = fmaf(wq.y, xv1.y, acc[o].y);
                acc[o].z = fmaf(wq.y, xv1.z, acc[o].z);
                acc[o].w = fmaf(wq.y, xv1.w, acc[o].w);
                acc[o].x = fmaf(wq.z, xv2.x, acc[o].x);
                acc[o].y = fmaf(wq.z, xv2.y, acc[o].y);
                acc[o].z = fmaf(wq.z, xv2.z, acc[o].z);
                acc[o].w = fmaf(wq.z, xv2.w, acc[o].w);
                acc[o].x = fmaf(wq.w, xv3.x, acc[o].x);
                acc[o].y = fmaf(wq.w, xv3.y, acc[o].y);
                acc[o].z = fmaf(wq.w, xv3.z, acc[o].z);
                acc[o].w = fmaf(wq.w, xv3.w, acc[o].w);
            }
        }
    }

    float* __restrict__ on = out + (size_t)n * CHIMG + (size_t)h * WW + w0;
#pragma unroll
    for (int o = 0; o < CH; ++o)
        *(f4*)(on + (size_t)o * IMG) = acc[o];   // 16B aligned
}

// ---------------- fixup kernel: recompute w in {0..3, 508..511} exactly -----
__global__ void diag_conv_fixup(const float* __restrict__ x,
                                const float* __restrict__ fw,
                                float* __restrict__ out)
{
    const int h  = blockIdx.x;
    const int n  = blockIdx.y;
    const int o  = threadIdx.x >> 3;
    const int wi = threadIdx.x & 7;
    const int w  = wi < 4 ? wi : (WW - 8 + wi);   // 0..3 or 508..511

    float s = 0.f;
#pragma unroll
    for (int k = 0; k < KK; ++k) {
        const int hh = h + k - 2;
        const int ww = w + k - 2;
        if ((unsigned)hh >= (unsigned)HH || (unsigned)ww >= (unsigned)WW) continue;
        const float* __restrict__ xp = x + (size_t)n * CHIMG + (size_t)hh * WW + ww;
#pragma unroll
        for (int i = 0; i < CH; ++i)
            s = fmaf(fw[(o * CH + i) * KK + k], xp[(size_t)i * IMG], s);
    }
    out[(size_t)(n * CH + o) * IMG + (size_t)h * WW + w] = s;
}

extern "C" void kernel_launch(void* const* d_in, const int* in_sizes, int n_in,
                              void* d_out, int out_size, void* d_ws, size_t ws_size,
                              hipStream_t stream)
{
    const float* x  = (const float*)d_in[0];
    const float* fw = (const float*)d_in[1];
    float* out      = (float*)d_out;

    diag_conv_main<<<dim3(4096), dim3(256), 0, stream>>>(x, fw, out);
    diag_conv_fixup<<<dim3(HH, 16), dim3(128), 0, stream>>>(x, fw, out);
}